// Round 1
// baseline (437.657 us; speedup 1.0000x reference)
//
#include <hip/hip_runtime.h>

// ---------------------------------------------------------------- constants
#define T_N   262144
#define D_IN  128
#define H_HID 256
#define A_DIM 8
#define GAMMA 0.99f
#define LMBD  0.95f
#define EPS_C 0.2f
#define C_GL  0.9405f                 // GAMMA*LMBD
#define W16C  0.37474927f             // C_GL^16
#define CHUNK 4096
#define NCHUNK 64                     // T_N / CHUNK
#define HALF_LOG_2PI 0.9189385332f

typedef __attribute__((ext_vector_type(8))) short short8;
typedef __attribute__((ext_vector_type(4))) float f32x4;

__device__ __forceinline__ unsigned short f2bf(float f) {
  unsigned int u = __float_as_uint(f);
  u += 0x7FFFu + ((u >> 16) & 1u);          // RNE
  return (unsigned short)(u >> 16);
}
__device__ __forceinline__ float bf2f(unsigned short h) {
  return __uint_as_float(((unsigned int)h) << 16);
}
__device__ __forceinline__ float fast_tanh(float x) {
  x = fminf(10.f, fmaxf(-10.f, x));
  float e = __expf(2.f * x);
  return 1.f - 2.f * __builtin_amdgcn_rcpf(e + 1.f);
}

// ---------------------------------------------------------------- prep:
// Wc1T/W1T: [H][D] bf16 (transposed, n-major) for B-fragments.
// H0: [16][256] bf16 head weights for critic (row0 = Wc2, rest 0)
// H1: [16][256] bf16 head weights for actor (rows0-7 = Wmu^T, 8-15 = Wlv^T)
__global__ __launch_bounds__(256) void k_prep(
    const float* __restrict__ Wc1, const float* __restrict__ W1,
    const float* __restrict__ Wc2, const float* __restrict__ Wmu,
    const float* __restrict__ Wlv,
    unsigned short* __restrict__ Wc1T, unsigned short* __restrict__ W1T,
    unsigned short* __restrict__ H0, unsigned short* __restrict__ H1) {
  int i = blockIdx.x * 256 + threadIdx.x;
  if (i < 32768) {
    int n = i >> 7, k = i & 127;
    Wc1T[i] = f2bf(Wc1[k * 256 + n]);
  } else if (i < 65536) {
    int j = i - 32768; int n = j >> 7, k = j & 127;
    W1T[j] = f2bf(W1[k * 256 + n]);
  } else if (i < 69632) {
    int j = i - 65536; int h = j >> 8, n = j & 255;
    H0[j] = (h == 0) ? f2bf(Wc2[n]) : (unsigned short)0;
  } else if (i < 73728) {
    int j = i - 69632; int h = j >> 8, n = j & 255;
    H1[j] = (h < 8) ? f2bf(Wmu[n * 8 + h]) : f2bf(Wlv[n * 8 + (h - 8)]);
  }
}

// ---------------------------------------------------------------- main:
// grid (T/64, 3). job 0: critic(state)->v0, 1: critic(next)->v1,
// job 2: actor(state)->ratio.  64 rows/block, 4 waves, wave w owns H-cols
// [w*64, w*64+64). MFMA 16x16x32 bf16; heads via a 2nd MFMA (16 heads = 1 M-tile).
__global__ __launch_bounds__(256) void k_main(
    const float* __restrict__ state, const float* __restrict__ next_state,
    const float* __restrict__ action, const float* __restrict__ beta_lp,
    const unsigned short* __restrict__ Wc1T, const unsigned short* __restrict__ W1T,
    const unsigned short* __restrict__ H0, const unsigned short* __restrict__ H1,
    const float* __restrict__ bc1, const float* __restrict__ b1,
    const float* __restrict__ bc2, const float* __restrict__ bmu,
    const float* __restrict__ blv,
    float* __restrict__ v0out, float* __restrict__ v1out,
    float* __restrict__ ratio) {
  const int job = blockIdx.y;
  const int r0  = blockIdx.x * 64;
  const int tid = threadIdx.x;
  const int lane = tid & 63;
  const int wv   = tid >> 6;         // wave id 0..3
  const int c    = lane & 15;
  const int quad = lane >> 4;

  __shared__ unsigned short sh_x[64 * 136];    // X tile bf16, stride 136
  __shared__ unsigned short sh_h[64 * 264];    // h tile bf16 row-major, stride 264
  __shared__ unsigned short sh_wh[16 * 264];   // head weights, stride 264
  __shared__ float sh_hb[64 * 16];             // head outputs [sample][head]

  const float* X = (job == 1) ? next_state : state;
  const unsigned short* WT = (job == 2) ? W1T : Wc1T;
  const float* bias = (job == 2) ? b1 : bc1;
  const unsigned short* HW = (job == 2) ? H1 : H0;

  // ---- stage X tile: 64 rows x 128 f32 -> bf16 LDS
  {
    const float4* Xv = (const float4*)(X + r0 * D_IN);
#pragma unroll
    for (int it = 0; it < 8; ++it) {
      int f4 = tid + it * 256;                  // 0..2047
      int row = f4 >> 5, c4 = f4 & 31;
      float4 v = Xv[f4];
      ushort4 u;
      u.x = f2bf(v.x); u.y = f2bf(v.y); u.z = f2bf(v.z); u.w = f2bf(v.w);
      *(ushort4*)(&sh_x[row * 136 + c4 * 4]) = u;
    }
#pragma unroll
    for (int it = 0; it < 16; ++it) {
      int j = tid + it * 256;                   // 0..4095
      sh_wh[(j >> 8) * 264 + (j & 255)] = HW[j];
    }
  }
  __syncthreads();

  // ---- preload B fragments (whole K=128 for this wave's 64 cols) into regs
  short8 bfrag[4][4];
  float bias_c[4];
#pragma unroll
  for (int ct = 0; ct < 4; ++ct) {
    int n = wv * 64 + ct * 16 + c;
    bias_c[ct] = bias[n];
#pragma unroll
    for (int ki = 0; ki < 4; ++ki)
      bfrag[ct][ki] = *(const short8*)(WT + n * 128 + ki * 32 + quad * 8);
  }

  // ---- main GEMM: 4 row-tiles of 16
#pragma unroll
  for (int rt = 0; rt < 4; ++rt) {
    f32x4 acc[4];
#pragma unroll
    for (int ct = 0; ct < 4; ++ct) acc[ct] = (f32x4){0.f, 0.f, 0.f, 0.f};
#pragma unroll
    for (int ki = 0; ki < 4; ++ki) {
      short8 a = *(const short8*)(&sh_x[(rt * 16 + c) * 136 + ki * 32 + quad * 8]);
#pragma unroll
      for (int ct = 0; ct < 4; ++ct)
        acc[ct] = __builtin_amdgcn_mfma_f32_16x16x32_bf16(a, bfrag[ct][ki], acc[ct], 0, 0, 0);
    }
    // epilogue: bias + tanh -> sh_h (row-major). D: row=quad*4+reg, col=lane&15
#pragma unroll
    for (int ct = 0; ct < 4; ++ct) {
      int col = wv * 64 + ct * 16 + c;
#pragma unroll
      for (int r = 0; r < 4; ++r) {
        int row = rt * 16 + quad * 4 + r;
        sh_h[row * 264 + col] = f2bf(fast_tanh(acc[ct][r] + bias_c[ct]));
      }
    }
  }
  __syncthreads();

  // ---- head GEMM: D2[head][sample] = Whead(16x256) @ h^T. wave w -> samples w*16..+15
  {
    f32x4 acc2 = (f32x4){0.f, 0.f, 0.f, 0.f};
#pragma unroll
    for (int ki = 0; ki < 8; ++ki) {
      short8 a2 = *(const short8*)(&sh_wh[c * 264 + ki * 32 + quad * 8]);           // A[m=head=c][k]
      short8 b2 = *(const short8*)(&sh_h[(wv * 16 + c) * 264 + ki * 32 + quad * 8]); // B[k][n=sample=c]
      acc2 = __builtin_amdgcn_mfma_f32_16x16x32_bf16(a2, b2, acc2, 0, 0, 0);
    }
    // D2: head = quad*4+reg, sample = wv*16 + c
    *((f32x4*)&sh_hb[(wv * 16 + c) * 16 + quad * 4]) = acc2;
  }
  __syncthreads();

  // ---- per-sample epilogue
  if (tid < 64) {
    int s = tid, t = r0 + s;
    if (job == 0) {
      v0out[t] = sh_hb[s * 16] + bc2[0];
    } else if (job == 1) {
      v1out[t] = sh_hb[s * 16] + bc2[0];
    } else {
      float slp = 0.f;
#pragma unroll
      for (int a = 0; a < A_DIM; ++a) {
        float mu = sh_hb[s * 16 + a] + bmu[a];
        float lv = sh_hb[s * 16 + 8 + a] + blv[a];
        float ac = action[t * A_DIM + a];
        float bl = beta_lp[t * A_DIM + a];
        float d = ac - mu;
        slp += -0.5f * d * d * __expf(-lv) - 0.5f * lv - HALF_LOG_2PI - bl;
      }
      ratio[t] = __expf(slp);
    }
  }
}

// ---------------------------------------------------------------- delta + per-chunk anchored sums
__global__ __launch_bounds__(256) void k_delta(
    const float* __restrict__ reward, const float* __restrict__ v0,
    const float* __restrict__ v1, float* __restrict__ delta,
    float* __restrict__ chunkS) {
  int j = blockIdx.x, k = threadIdx.x;
  int base = j * CHUNK + k * 16;
  float s = 0.f, wgt = 1.f;
#pragma unroll
  for (int i = 0; i < 16; ++i) {
    float d = reward[base + i] + GAMMA * v1[base + i] - v0[base + i];
    delta[base + i] = d;
    s += wgt * d;
    wgt *= C_GL;
  }
  __shared__ float red[256];
  red[k] = __powf(W16C, (float)k) * s;
  __syncthreads();
  for (int off = 128; off > 0; off >>= 1) {
    if (k < off) red[k] += red[k + off];
    __syncthreads();
  }
  if (k == 0) chunkS[j] = red[0];
}

// ---------------------------------------------------------------- cross-chunk carries (c^4096 == 0 in fp32)
__global__ void k_carry(const float* __restrict__ chunkS, float* __restrict__ carry) {
  if (threadIdx.x == 0) {
    float g = 0.f;
    for (int j = NCHUNK - 1; j >= 0; --j) {
      carry[j] = g;                       // g at start of chunk j+1
      g = chunkS[j] + 0.0f * g;           // c^CHUNK underflows fp32 -> exactly 0
    }
  }
}

// ---------------------------------------------------------------- apply GAE scan, adv, Σadv, Σadv²
__global__ __launch_bounds__(256) void k_gae(
    const float* __restrict__ delta, const float* __restrict__ value,
    const float* __restrict__ carry, float* __restrict__ adv,
    float* __restrict__ accs) {
  int j = blockIdx.x, k = threadIdx.x;
  int base = j * CHUNK + k * 16;
  float d[16];
  float s = 0.f, wgt = 1.f;
#pragma unroll
  for (int i = 0; i < 16; ++i) {
    d[i] = delta[base + i];
    s += wgt * d[i];
    wgt *= C_GL;
  }
  __shared__ float Ss[256], Sw[256];
  Ss[k] = s; Sw[k] = W16C;
  __syncthreads();
  // Kogge-Stone inclusive suffix scan with (sum, weight) composition
  for (int dd = 1; dd < 256; dd <<= 1) {
    bool has = (k + dd) < 256;
    float ns = 0.f, nw = 0.f;
    if (has) { ns = Ss[k] + Sw[k] * Ss[k + dd]; nw = Sw[k] * Sw[k + dd]; }
    __syncthreads();
    if (has) { Ss[k] = ns; Sw[k] = nw; }
    __syncthreads();
  }
  float g = ((k < 255) ? Ss[k + 1] : 0.f) + __powf(W16C, (float)(255 - k)) * carry[j];
  float sa = 0.f, sq = 0.f;
#pragma unroll
  for (int i = 15; i >= 0; --i) {
    g = d[i] + C_GL * g;                 // ret at base+i
    float a = g - value[base + i];
    adv[base + i] = a;
    sa += a; sq += a * a;
  }
  __syncthreads();
  Ss[k] = sa; Sw[k] = sq;
  __syncthreads();
  for (int off = 128; off > 0; off >>= 1) {
    if (k < off) { Ss[k] += Ss[k + off]; Sw[k] += Sw[k + off]; }
    __syncthreads();
  }
  if (k == 0) {
    atomicAdd(&accs[0], Ss[0]);          // Σ adv
    atomicAdd(&accs[1], Sw[0]);          // Σ adv²  (== critic_loss)
  }
}

// ---------------------------------------------------------------- actor loss
__global__ __launch_bounds__(256) void k_actor(
    const float* __restrict__ adv, const float* __restrict__ ratio,
    float* __restrict__ accs) {
  int t = blockIdx.x * 256 + threadIdx.x;
  float sum  = accs[0];
  float mean = sum * (1.f / (float)T_N);
  float var  = (accs[1] - sum * mean) / (float)(T_N - 1);
  float inv  = 1.f / (sqrtf(var) + 1e-7f);
  float a = (adv[t] - mean) * inv;
  float r = ratio[t];
  float rc = fminf(fmaxf(r, 1.f - EPS_C), 1.f + EPS_C);
  float term = -fminf(r * a, rc * a);
  __shared__ float red[256];
  int k = threadIdx.x;
  red[k] = term;
  __syncthreads();
  for (int off = 128; off > 0; off >>= 1) {
    if (k < off) red[k] += red[k + off];
    __syncthreads();
  }
  if (k == 0) atomicAdd(&accs[2], red[0]);
}

__global__ void k_fin(const float* __restrict__ accs, float* __restrict__ out) {
  out[0] = accs[2] + accs[1];            // actor_loss + critic_loss
}

// ---------------------------------------------------------------- launch
extern "C" void kernel_launch(void* const* d_in, const int* in_sizes, int n_in,
                              void* d_out, int out_size, void* d_ws, size_t ws_size,
                              hipStream_t stream) {
  const float* state      = (const float*)d_in[0];
  const float* next_state = (const float*)d_in[1];
  const float* action     = (const float*)d_in[2];
  const float* beta_lp    = (const float*)d_in[3];
  const float* reward     = (const float*)d_in[4];
  const float* W1   = (const float*)d_in[5];
  const float* b1   = (const float*)d_in[6];
  const float* Wmu  = (const float*)d_in[7];
  const float* bmu  = (const float*)d_in[8];
  const float* Wlv  = (const float*)d_in[9];
  const float* blv  = (const float*)d_in[10];
  const float* Wc1  = (const float*)d_in[11];
  const float* bc1  = (const float*)d_in[12];
  const float* Wc2  = (const float*)d_in[13];
  const float* bc2  = (const float*)d_in[14];

  char* ws = (char*)d_ws;
  size_t o = 0;
  unsigned short* Wc1T = (unsigned short*)(ws + o); o += 65536;
  unsigned short* W1T  = (unsigned short*)(ws + o); o += 65536;
  unsigned short* H0   = (unsigned short*)(ws + o); o += 8192;
  unsigned short* H1   = (unsigned short*)(ws + o); o += 8192;
  float* v0    = (float*)(ws + o); o += (size_t)T_N * 4;
  float* v1    = (float*)(ws + o); o += (size_t)T_N * 4;
  float* ratio = (float*)(ws + o); o += (size_t)T_N * 4;
  float* delta = (float*)(ws + o); o += (size_t)T_N * 4;
  float* adv   = (float*)(ws + o); o += (size_t)T_N * 4;
  float* chunkS = (float*)(ws + o); o += 256;
  float* carry  = (float*)(ws + o); o += 256;
  float* accs   = (float*)(ws + o); o += 256;

  hipMemsetAsync(accs, 0, 16, stream);

  k_prep<<<288, 256, 0, stream>>>(Wc1, W1, Wc2, Wmu, Wlv, Wc1T, W1T, H0, H1);

  dim3 gmain(T_N / 64, 3);
  k_main<<<gmain, 256, 0, stream>>>(state, next_state, action, beta_lp,
                                    Wc1T, W1T, H0, H1, bc1, b1, bc2, bmu, blv,
                                    v0, v1, ratio);

  k_delta<<<NCHUNK, 256, 0, stream>>>(reward, v0, v1, delta, chunkS);
  k_carry<<<1, 64, 0, stream>>>(chunkS, carry);
  k_gae<<<NCHUNK, 256, 0, stream>>>(delta, v0, carry, adv, accs);
  k_actor<<<T_N / 256, 256, 0, stream>>>(adv, ratio, accs);
  k_fin<<<1, 1, 0, stream>>>(accs, (float*)d_out);
}